// Round 1
// baseline (267.720 us; speedup 1.0000x reference)
//
#include <hip/hip_runtime.h>
#include <math.h>

// Problem constants (fixed by the reference)
constexpr int kEmb    = 128;
constexpr int kRegion = 7;
constexpr int kRadius = 3;
constexpr int kBatch  = 32;
constexpr int kSeq    = 1024;
constexpr int kPos    = kBatch * kSeq;
constexpr int kHalf   = kPos / 2;        // 16384

typedef float f32x4 __attribute__((ext_vector_type(4)));  // native vec for NT store

// h[b,s,e] = max_r U_full[win*7+r][e] * W_full[t][e]
//   W_full[t]     = (t > 0) ? W[t-1]         : 0
//   U_full[t*7+r] = (t > 0) ? U[(t-1)*7 + r] : 0   (covers padding AND token 0)
//
// R5: the timed region is {2 harness fills (~214us, fixed) + kernel (~35us)}.
// Kernel is a cold-L3 512B-row gather at ~68% of streaming ceiling; attack the
// controllable overhead:
//  (a) token windows fetched with ONE guarded dword load per position (lane r
//      loads token r), broadcast via __shfl within the 32-lane group -> VMEM
//      instructions per wave drop ~32 -> ~20 (the ds pipe is idle anyway).
//  (b) all gather/store addresses computed as unsigned BYTE offsets off the
//      base pointer (everything fits in 32 bits: U spans 179MB) -> saddr-form
//      global_load_dwordx4 with 32-bit voffset, no v_lshl_add_u64 chains.
// Keep the R4 two-position software pipeline (p and p+kPos/2): MLP per SIMD is
// already far above what 900cy HBM latency needs; 4-pos would only cost VGPRs.
// Out-stores stay nontemporal (output never re-read).
__global__ __launch_bounds__(256) void region_encoder_kernel(
    const int*   __restrict__ seq,   // (32, 1024)
    const float* __restrict__ W,     // (49999, 128)
    const float* __restrict__ U,     // (349993, 128)
    float*       __restrict__ out)   // (32, 1024, 128)
{
    const int lane = threadIdx.x & 31;
    const int grp  = threadIdx.x >> 5;           // 0..7
    const int p0   = blockIdx.x * 8 + grp;       // 0 .. kHalf-1
    const int p1   = p0 + kHalf;
    const int s0   = p0 & (kSeq - 1);
    const int s1   = p1 & (kSeq - 1);
    const unsigned laneB = (unsigned)lane * 16u; // byte offset of this lane's float4

    // ---- one guarded dword load per position fetches the whole 7-token window ----
    // lane r (r<7) holds window token r; other lanes hold 0.
    int tv0 = 0, tv1 = 0;
    {
        const int sp0 = s0 - kRadius + lane;
        if (lane < kRegion && (unsigned)sp0 < (unsigned)kSeq)
            tv0 = *(const int*)((const char*)seq + (unsigned)(p0 - s0 + sp0) * 4u);
        const int sp1 = s1 - kRadius + lane;
        if (lane < kRegion && (unsigned)sp1 < (unsigned)kSeq)
            tv1 = *(const int*)((const char*)seq + (unsigned)(p1 - s1 + sp1) * 4u);
    }

    // ---- broadcast the windows to all 32 lanes of the group (ds pipe) ----
    int tok0[kRegion], tok1[kRegion];
#pragma unroll
    for (int r = 0; r < kRegion; ++r) {
        tok0[r] = __shfl(tv0, r, 32);
        tok1[r] = __shfl(tv1, r, 32);
    }

    // ---- W rows for both center tokens (32-bit byte offsets) ----
    const int t0 = tok0[kRadius];
    const int t1 = tok1[kRadius];
    f32x4 wv0 = {0.f, 0.f, 0.f, 0.f};
    f32x4 wv1 = {0.f, 0.f, 0.f, 0.f};
    if (t0 > 0)
        wv0 = *(const f32x4*)((const char*)W + ((unsigned)(t0 - 1) * 512u + laneB));
    if (t1 > 0)
        wv1 = *(const f32x4*)((const char*)W + ((unsigned)(t1 - 1) * 512u + laneB));

    // ---- all 14 U-row gathers, issued back-to-back ----
    f32x4 uv0[kRegion], uv1[kRegion];
#pragma unroll
    for (int r = 0; r < kRegion; ++r) {
        uv0[r] = (f32x4){0.f, 0.f, 0.f, 0.f};
        if (tok0[r] > 0) {
            const unsigned off = ((unsigned)(tok0[r] - 1) * 7u + (unsigned)r) * 512u + laneB;
            uv0[r] = *(const f32x4*)((const char*)U + off);
        }
    }
#pragma unroll
    for (int r = 0; r < kRegion; ++r) {
        uv1[r] = (f32x4){0.f, 0.f, 0.f, 0.f};
        if (tok1[r] > 0) {
            const unsigned off = ((unsigned)(tok1[r] - 1) * 7u + (unsigned)r) * 512u + laneB;
            uv1[r] = *(const f32x4*)((const char*)U + off);
        }
    }

    // ---- consume position 0 ----
    f32x4 m0 = uv0[0] * wv0;
#pragma unroll
    for (int r = 1; r < kRegion; ++r) {
        const f32x4 p = uv0[r] * wv0;
        m0.x = fmaxf(m0.x, p.x);
        m0.y = fmaxf(m0.y, p.y);
        m0.z = fmaxf(m0.z, p.z);
        m0.w = fmaxf(m0.w, p.w);
    }
    __builtin_nontemporal_store(
        m0, (f32x4*)((char*)out + ((unsigned)p0 * 512u + laneB)));

    // ---- consume position 1 ----
    f32x4 m1 = uv1[0] * wv1;
#pragma unroll
    for (int r = 1; r < kRegion; ++r) {
        const f32x4 p = uv1[r] * wv1;
        m1.x = fmaxf(m1.x, p.x);
        m1.y = fmaxf(m1.y, p.y);
        m1.z = fmaxf(m1.z, p.z);
        m1.w = fmaxf(m1.w, p.w);
    }
    __builtin_nontemporal_store(
        m1, (f32x4*)((char*)out + ((unsigned)p1 * 512u + laneB)));
}

extern "C" void kernel_launch(void* const* d_in, const int* in_sizes, int n_in,
                              void* d_out, int out_size, void* d_ws, size_t ws_size,
                              hipStream_t stream) {
    const int*   seq = (const int*)d_in[0];
    const float* W   = (const float*)d_in[1];
    const float* U   = (const float*)d_in[2];
    float*       out = (float*)d_out;

    const int blocks = kHalf / 8;                // 2048 blocks, 16 positions each
    region_encoder_kernel<<<dim3(blocks), dim3(256), 0, stream>>>(seq, W, U, out);
}